// Round 4
// baseline (449.747 us; speedup 1.0000x reference)
//
#include <hip/hip_runtime.h>
#include <math.h>

#define B_   16
#define S_   8192
#define KVD  512
#define E_   512
#define H_   8
#define D_   64

// ws float layout (contiguous zero region after qk_vec)
#define OFF_QKVEC   0         // 65536  qk_vec[b][h][c]
#define OFF_LACC    65536     // 128    l_acc[b][h]
#define OFF_CTXACC  65664     // 65536  ctx_acc[b][h][c] (unnormalized)
#define OFF_CTXBUF  131200    // 8192   ctx_buf[b][e]
#define ZERO_START  OFF_LACC
#define ZERO_COUNT  73856     // l_acc + ctx_acc + ctx_buf

// ---------------------------------------------------------------------------
// k_prep: blocks [0,64): fold q through Wk -> qk_vec (each block recomputes
// its q slice; bk dropped: softmax-invariant). blocks [64,145): zero
// accumulators + d_out.
// ---------------------------------------------------------------------------
__global__ __launch_bounds__(256) void k_prep(const float* __restrict__ query,
                                              const float* __restrict__ Wq,
                                              const float* __restrict__ bq,
                                              const float* __restrict__ Wk,
                                              float* __restrict__ wsf,
                                              float* __restrict__ out) {
    const int blk = blockIdx.x;
    const int tid = threadIdx.x;

    if (blk >= 64) {
        int i = (blk - 64) * 256 + tid;  // float4 index
        const int nws4 = ZERO_COUNT / 4; // 18464
        if (i < nws4) {
            *(float4*)&wsf[ZERO_START + i * 4] = make_float4(0.f, 0.f, 0.f, 0.f);
        } else if (i < nws4 + (B_ * E_) / 4) {
            *(float4*)&out[(size_t)(i - nws4) * 4] = make_float4(0.f, 0.f, 0.f, 0.f);
        }
        return;
    }

    const int cc = blk & 7, h = blk >> 3;
    float* qk_vec = wsf + OFF_QKVEC;

    __shared__ float qbuf[16 * 512];   // 32 KB raw query
    __shared__ float wk[64 * 65];      // Wk tile, padded
    __shared__ float qh[16 * 64];      // scaled q slice for head h

    // stage query[16][512] (float4) and Wk[cc*64..+63][h*64..+63]
    #pragma unroll
    for (int k = 0; k < 8; ++k) {
        int f4i = tid + k * 256;       // 2048 float4
        *(float4*)&qbuf[f4i * 4] = *(const float4*)&query[(size_t)f4i * 4];
    }
    #pragma unroll
    for (int k = 0; k < 4; ++k) {
        int f4i = tid + k * 256;       // 1024 float4
        int row = f4i >> 4, d4 = f4i & 15;
        float4 v = *(const float4*)&Wk[(size_t)(cc * 64 + row) * E_ + h * D_ + d4 * 4];
        wk[row * 65 + d4 * 4 + 0] = v.x;
        wk[row * 65 + d4 * 4 + 1] = v.y;
        wk[row * 65 + d4 * 4 + 2] = v.z;
        wk[row * 65 + d4 * 4 + 3] = v.w;
    }
    __syncthreads();

    // phase 1: q[b][h*64+d] for b = w*4..w*4+3, d = lane
    const int d = tid & 63, w = tid >> 6;
    {
        float acc[4] = {0.f, 0.f, 0.f, 0.f};
        const float* wq = Wq + h * D_ + d;
        for (int k = 0; k < 512; k += 4) {
            #pragma unroll
            for (int kk = 0; kk < 4; ++kk) {
                float wv = wq[(size_t)(k + kk) * E_];
                #pragma unroll
                for (int i = 0; i < 4; ++i)
                    acc[i] = fmaf(qbuf[(w * 4 + i) * 512 + k + kk], wv, acc[i]);
            }
        }
        float bqv = bq[h * D_ + d];
        #pragma unroll
        for (int i = 0; i < 4; ++i)
            qh[(w * 4 + i) * 64 + d] = (acc[i] + bqv) * 0.125f;  // 1/sqrt(64)
    }
    __syncthreads();

    // phase 2: qk_vec[b][h][cc*64 + c] = sum_d qh[b][d] * wk[c][d]
    {
        const int c_local = tid & 63;
        float acc[4] = {0.f, 0.f, 0.f, 0.f};
        for (int dd = 0; dd < 64; ++dd) {
            float wv = wk[c_local * 65 + dd];
            #pragma unroll
            for (int i = 0; i < 4; ++i)
                acc[i] = fmaf(qh[(w * 4 + i) * 64 + dd], wv, acc[i]);
        }
        #pragma unroll
        for (int i = 0; i < 4; ++i) {
            int b = w * 4 + i;
            qk_vec[((size_t)b * H_ + h) * KVD + cc * 64 + c_local] = acc[i];
        }
    }
}

// ---------------------------------------------------------------------------
// k_attn v8: async-staged streaming attention.
//
// R3 post-mortem: register double-buffer (R0) and 2-wave occupancy (R3) both
// land at ~100 us (~2.7 TB/s) — the compiler's scheduling of the register
// prefetch around the dependent softmax chain exposes HBM latency either way,
// and R1 proved deeper register pipelining spills (311 MB scratch).
//
// v8 decouples prefetch depth from VGPRs: per-wave LDS ring of NSTAGE=3 slots
// (RB=2 rows = 4 KB each), filled by __builtin_amdgcn_global_load_lds
// (vmcnt-tracked, no destination VGPRs, 4 instrs/slot). Before consuming the
// oldest slot we issue an explicit counted `s_waitcnt vmcnt(8)` — the two
// newer slots stay in flight across the whole compute chain, so HBM streams
// regardless of compiler scheduling. No barriers needed: slots are
// wave-private. kv register buffer shrinks to one (16 VGPR).
// LDS: 48 KB ring + 17.4 KB scr + lbuf ≈ 66 KB -> 2 blocks/CU.
// ---------------------------------------------------------------------------
#define SROW 68
#define RB   2
#define NSTAGE 3

__device__ __forceinline__ void stage_slot(const float* base, int it,
                                           float* slot, int lane) {
    // 4 x global_load_lds dwordx4: 2 rows x 2 halves, 64 lanes x 16 B = 1 KB each.
    // LDS dest is wave-uniform base (hw adds lane*16); global src is per-lane.
    #pragma unroll
    for (int r = 0; r < RB; ++r) {
        const float* rowp = base + (size_t)(it * RB + r) * KVD;
        __builtin_amdgcn_global_load_lds(
            (__attribute__((address_space(1))) unsigned int*)(rowp + lane * 4),
            (__attribute__((address_space(3))) unsigned int*)(slot + r * 512),
            16, 0, 0);
        __builtin_amdgcn_global_load_lds(
            (__attribute__((address_space(1))) unsigned int*)(rowp + 256 + lane * 4),
            (__attribute__((address_space(3))) unsigned int*)(slot + r * 512 + 256),
            16, 0, 0);
    }
}

__device__ __forceinline__ void attn_process(const float (&kvr)[RB][8],
                                             const float (&qk)[H_][8],
                                             float (&ctx)[H_][8], float& l_run,
                                             float* wscr, int lane) {
    const int seg = lane & 7;
    const int hme = lane >> 3;
    // per-lane dot partials -> LDS scatter (consecutive lanes -> consecutive addrs)
    #pragma unroll
    for (int r = 0; r < RB; ++r)
        #pragma unroll
        for (int h = 0; h < H_; ++h) {
            float p = 0.f;
            #pragma unroll
            for (int j = 0; j < 8; ++j) p = fmaf(kvr[r][j], qk[h][j], p);
            wscr[(r * H_ + h) * SROW + lane] = p;
        }
    // fence: scatter above MUST complete (program order) before gather below.
    asm volatile("" ::: "memory");
    // gather 8 partials for (row r, head lane>>3), butterfly over seg, exp
    const float* rdb = wscr + hme * SROW + seg * 8;
    float e4[RB];
    #pragma unroll
    for (int r = 0; r < RB; ++r) {
        const float* p = rdb + r * H_ * SROW;
        float4 x = *(const float4*)p;
        float4 y = *(const float4*)(p + 4);
        float s = ((x.x + x.y) + (x.z + x.w)) + ((y.x + y.y) + (y.z + y.w));
        s += __shfl_xor(s, 1);
        s += __shfl_xor(s, 2);
        s += __shfl_xor(s, 4);
        e4[r] = __expf(s);
        l_run += e4[r];
    }
    // accumulate: fetch head-h weight via shfl, fma into ctx
    #pragma unroll
    for (int r = 0; r < RB; ++r)
        #pragma unroll
        for (int h = 0; h < H_; ++h) {
            float wv = __shfl(e4[r], h * 8 + seg);
            #pragma unroll
            for (int j = 0; j < 8; ++j)
                ctx[h][j] = fmaf(wv, kvr[r][j], ctx[h][j]);
        }
}

template <int NC>
__global__ __launch_bounds__(256, 2) void k_attn(const float* __restrict__ kv,
                                                 const float* __restrict__ qk_vec,
                                                 float* __restrict__ ctx_acc,
                                                 float* __restrict__ l_acc) {
    constexpr int CHUNK = S_ / NC;         // NC=32 -> 256 rows/block
    constexpr int RPW = CHUNK / 4;         // 64 rows/wave
    constexpr int NIT = RPW / RB;          // 32 processes
    constexpr int SPW = RB * H_ * SROW;    // 1088
    constexpr int SLOT = RB * 512;         // floats per ring slot

    __shared__ __align__(16) float ring[4][NSTAGE][SLOT];  // 48 KB (wave-private slots)
    __shared__ __align__(16) float scr[4 * SPW];           // 17408 B; reused as cbuf
    __shared__ float lbuf[32];

    const int tid = threadIdx.x;
    const int lane = tid & 63;
    const int w = tid >> 6;
    const int nc = blockIdx.x, b = blockIdx.y;
    const int hme = lane >> 3, seg = lane & 7;

    float qk[H_][8];
    {
        const float* qb = qk_vec + (size_t)b * H_ * KVD;
        #pragma unroll
        for (int h = 0; h < H_; ++h) {
            float4 v0 = *(const float4*)&qb[h * KVD + lane * 4];
            float4 v1 = *(const float4*)&qb[h * KVD + 256 + lane * 4];
            qk[h][0] = v0.x; qk[h][1] = v0.y; qk[h][2] = v0.z; qk[h][3] = v0.w;
            qk[h][4] = v1.x; qk[h][5] = v1.y; qk[h][6] = v1.z; qk[h][7] = v1.w;
        }
    }

    float ctx[H_][8];
    #pragma unroll
    for (int h = 0; h < H_; ++h)
        #pragma unroll
        for (int j = 0; j < 8; ++j) ctx[h][j] = 0.f;
    float l_run = 0.f;

    float* wscr = scr + w * SPW;
    float* myring = &ring[w][0][0];
    const float* kvbase = kv + ((size_t)b * S_ + (size_t)nc * CHUNK + (size_t)w * RPW) * KVD;

    // prologue: fill the 3-slot ring (12 load instrs in flight)
    stage_slot(kvbase, 0, myring + 0 * SLOT, lane);
    stage_slot(kvbase, 1, myring + 1 * SLOT, lane);
    stage_slot(kvbase, 2, myring + 2 * SLOT, lane);

    int sl = 0;
    #pragma unroll 1
    for (int it = 0; it < NIT; ++it) {
        // oldest slot's 4 loads retired; 2 newer slots (8 instrs) stay in flight
        asm volatile("s_waitcnt vmcnt(8)" ::: "memory");
        float* slot = myring + sl * SLOT;
        float kvr[RB][8];
        #pragma unroll
        for (int r = 0; r < RB; ++r) {
            float4 v0 = *(const float4*)&slot[r * 512 + lane * 4];
            float4 v1 = *(const float4*)&slot[r * 512 + 256 + lane * 4];
            kvr[r][0] = v0.x; kvr[r][1] = v0.y; kvr[r][2] = v0.z; kvr[r][3] = v0.w;
            kvr[r][4] = v1.x; kvr[r][5] = v1.y; kvr[r][6] = v1.z; kvr[r][7] = v1.w;
        }
        // reuse this slot for it+NSTAGE: ds_reads above are issued (in order)
        // before these loads; their data returns ~HBM-latency later.
        if (it + NSTAGE < NIT) stage_slot(kvbase, it + NSTAGE, slot, lane);
        attn_process(kvr, qk, ctx, l_run, wscr, lane);
        sl = (sl + 1 == NSTAGE) ? 0 : sl + 1;
    }

    // ---- block merge (plain sums), then global atomics
    if (seg == 0) lbuf[w * 8 + hme] = l_run;
    __syncthreads();
    float* cbuf = scr;  // 4096 floats: cbuf[h*512 + c]
    if (w == 0) {
        #pragma unroll
        for (int h = 0; h < H_; ++h) {
            *(float4*)&cbuf[h * KVD + lane * 4] =
                make_float4(ctx[h][0], ctx[h][1], ctx[h][2], ctx[h][3]);
            *(float4*)&cbuf[h * KVD + 256 + lane * 4] =
                make_float4(ctx[h][4], ctx[h][5], ctx[h][6], ctx[h][7]);
        }
    }
    __syncthreads();
    if (w != 0) {
        #pragma unroll
        for (int h = 0; h < H_; ++h) {
            #pragma unroll
            for (int j = 0; j < 4; ++j)
                atomicAdd(&cbuf[h * KVD + lane * 4 + j], ctx[h][j]);
            #pragma unroll
            for (int j = 4; j < 8; ++j)
                atomicAdd(&cbuf[h * KVD + 256 + lane * 4 + (j - 4)], ctx[h][j]);
        }
    }
    __syncthreads();
    size_t gbase = (size_t)b * (H_ * KVD);
    #pragma unroll
    for (int k = 0; k < 16; ++k)
        atomicAdd(&ctx_acc[gbase + k * 256 + tid], cbuf[k * 256 + tid]);
    if (tid < H_) {
        float L = lbuf[tid] + lbuf[8 + tid] + lbuf[16 + tid] + lbuf[24 + tid];
        atomicAdd(&l_acc[b * H_ + tid], L);
    }
}

// ---------------------------------------------------------------------------
// k_ctx: ctx_buf[b][e] += (sum_{c chunk} ctx_acc[b,h(e),c]*Wv[c][e]) / l[b,h]
//        (+ bv[e] on kc==0).  grid (kc=4, b=16) x 512
// ---------------------------------------------------------------------------
__global__ __launch_bounds__(512) void k_ctx(const float* __restrict__ ctx_acc,
                                             const float* __restrict__ l_acc,
                                             const float* __restrict__ Wv,
                                             const float* __restrict__ bv,
                                             float* __restrict__ ctx_buf) {
    const int kc = blockIdx.x, b = blockIdx.y;
    const int e = threadIdx.x;
    const int h = e >> 6;
    const float inv = 1.0f / l_acc[b * H_ + h];
    const float* ca = ctx_acc + ((size_t)b * H_ + h) * KVD + kc * 128;
    const float* wv = Wv + (size_t)(kc * 128) * E_ + e;
    float a0 = 0.f, a1 = 0.f, a2 = 0.f, a3 = 0.f;
    for (int c = 0; c < 128; c += 4) {
        a0 = fmaf(ca[c],     wv[(size_t)(c)     * E_], a0);
        a1 = fmaf(ca[c + 1], wv[(size_t)(c + 1) * E_], a1);
        a2 = fmaf(ca[c + 2], wv[(size_t)(c + 2) * E_], a2);
        a3 = fmaf(ca[c + 3], wv[(size_t)(c + 3) * E_], a3);
    }
    float val = ((a0 + a1) + (a2 + a3)) * inv;
    if (kc == 0) val += bv[e];
    atomicAdd(&ctx_buf[(size_t)b * E_ + e], val);
}

// ---------------------------------------------------------------------------
// k_o: out[b][e] += sum_{i chunk} ctx_buf[b][i]*Wo[i][e] (+ bo[e] on kc==0)
// grid (kc=4, b=16) x 512
// ---------------------------------------------------------------------------
__global__ __launch_bounds__(512) void k_o(const float* __restrict__ ctx_buf,
                                           const float* __restrict__ Wo,
                                           const float* __restrict__ bo,
                                           float* __restrict__ out) {
    const int kc = blockIdx.x, b = blockIdx.y;
    const int e = threadIdx.x;
    const float* cs = ctx_buf + (size_t)b * E_ + kc * 128;
    const float* wo = Wo + (size_t)(kc * 128) * E_ + e;
    float a0 = 0.f, a1 = 0.f, a2 = 0.f, a3 = 0.f;
    for (int k = 0; k < 128; k += 4) {
        a0 = fmaf(cs[k],     wo[(size_t)(k)     * E_], a0);
        a1 = fmaf(cs[k + 1], wo[(size_t)(k + 1) * E_], a1);
        a2 = fmaf(cs[k + 2], wo[(size_t)(k + 2) * E_], a2);
        a3 = fmaf(cs[k + 3], wo[(size_t)(k + 3) * E_], a3);
    }
    float val = (a0 + a1) + (a2 + a3);
    if (kc == 0) val += bo[e];
    atomicAdd(&out[(size_t)b * E_ + e], val);
}

// ---------------------------------------------------------------------------
extern "C" void kernel_launch(void* const* d_in, const int* in_sizes, int n_in,
                              void* d_out, int out_size, void* d_ws, size_t ws_size,
                              hipStream_t stream) {
    const float* query = (const float*)d_in[0];
    const float* kv    = (const float*)d_in[1];
    const float* Wq    = (const float*)d_in[2];
    const float* bq    = (const float*)d_in[3];
    const float* Wk    = (const float*)d_in[4];
    // d_in[5] = bk: softmax-invariant per (b,h) -> unused
    const float* Wv    = (const float*)d_in[6];
    const float* bv    = (const float*)d_in[7];
    const float* Wo    = (const float*)d_in[8];
    const float* bo    = (const float*)d_in[9];
    float* out = (float*)d_out;
    float* wsf = (float*)d_ws;

    float* qk_vec  = wsf + OFF_QKVEC;
    float* l_acc   = wsf + OFF_LACC;
    float* ctx_acc = wsf + OFF_CTXACC;
    float* ctx_buf = wsf + OFF_CTXBUF;

    constexpr int NC = 32;  // 512 blocks; 2 blocks/CU resident (2 waves/SIMD)

    k_prep<<<145, 256, 0, stream>>>(query, Wq, bq, Wk, wsf, out);
    k_attn<NC><<<dim3(NC, B_), 256, 0, stream>>>(kv, qk_vec, ctx_acc, l_acc);
    k_ctx<<<dim3(4, B_), 512, 0, stream>>>(ctx_acc, l_acc, Wv, bv, ctx_buf);
    k_o<<<dim3(4, B_), 512, 0, stream>>>(ctx_buf, Wo, bo, out);
}

// Round 5
// 432.390 us; speedup vs baseline: 1.0401x; 1.0401x over previous
//
#include <hip/hip_runtime.h>
#include <math.h>

#define B_   16
#define S_   8192
#define KVD  512
#define E_   512
#define H_   8
#define D_   64

// ws float layout (contiguous zero region after qk_vec)
#define OFF_QKVEC   0         // 65536  qk_vec[b][h][c]
#define OFF_LACC    65536     // 128    l_acc[b][h]
#define OFF_CTXACC  65664     // 65536  ctx_acc[b][h][c] (unnormalized)
#define OFF_CTXBUF  131200    // 8192   ctx_buf[b][e]
#define ZERO_START  OFF_LACC
#define ZERO_COUNT  73856     // l_acc + ctx_acc + ctx_buf

// ---------------------------------------------------------------------------
// k_prep: blocks [0,64): fold q through Wk -> qk_vec (each block recomputes
// its q slice; bk dropped: softmax-invariant). blocks [64,145): zero
// accumulators + d_out.
// ---------------------------------------------------------------------------
__global__ __launch_bounds__(256) void k_prep(const float* __restrict__ query,
                                              const float* __restrict__ Wq,
                                              const float* __restrict__ bq,
                                              const float* __restrict__ Wk,
                                              float* __restrict__ wsf,
                                              float* __restrict__ out) {
    const int blk = blockIdx.x;
    const int tid = threadIdx.x;

    if (blk >= 64) {
        int i = (blk - 64) * 256 + tid;  // float4 index
        const int nws4 = ZERO_COUNT / 4; // 18464
        if (i < nws4) {
            *(float4*)&wsf[ZERO_START + i * 4] = make_float4(0.f, 0.f, 0.f, 0.f);
        } else if (i < nws4 + (B_ * E_) / 4) {
            *(float4*)&out[(size_t)(i - nws4) * 4] = make_float4(0.f, 0.f, 0.f, 0.f);
        }
        return;
    }

    const int cc = blk & 7, h = blk >> 3;
    float* qk_vec = wsf + OFF_QKVEC;

    __shared__ float qbuf[16 * 512];   // 32 KB raw query
    __shared__ float wk[64 * 65];      // Wk tile, padded
    __shared__ float qh[16 * 64];      // scaled q slice for head h

    // stage query[16][512] (float4) and Wk[cc*64..+63][h*64..+63]
    #pragma unroll
    for (int k = 0; k < 8; ++k) {
        int f4i = tid + k * 256;       // 2048 float4
        *(float4*)&qbuf[f4i * 4] = *(const float4*)&query[(size_t)f4i * 4];
    }
    #pragma unroll
    for (int k = 0; k < 4; ++k) {
        int f4i = tid + k * 256;       // 1024 float4
        int row = f4i >> 4, d4 = f4i & 15;
        float4 v = *(const float4*)&Wk[(size_t)(cc * 64 + row) * E_ + h * D_ + d4 * 4];
        wk[row * 65 + d4 * 4 + 0] = v.x;
        wk[row * 65 + d4 * 4 + 1] = v.y;
        wk[row * 65 + d4 * 4 + 2] = v.z;
        wk[row * 65 + d4 * 4 + 3] = v.w;
    }
    __syncthreads();

    // phase 1: q[b][h*64+d] for b = w*4..w*4+3, d = lane
    const int d = tid & 63, w = tid >> 6;
    {
        float acc[4] = {0.f, 0.f, 0.f, 0.f};
        const float* wq = Wq + h * D_ + d;
        for (int k = 0; k < 512; k += 4) {
            #pragma unroll
            for (int kk = 0; kk < 4; ++kk) {
                float wv = wq[(size_t)(k + kk) * E_];
                #pragma unroll
                for (int i = 0; i < 4; ++i)
                    acc[i] = fmaf(qbuf[(w * 4 + i) * 512 + k + kk], wv, acc[i]);
            }
        }
        float bqv = bq[h * D_ + d];
        #pragma unroll
        for (int i = 0; i < 4; ++i)
            qh[(w * 4 + i) * 64 + d] = (acc[i] + bqv) * 0.125f;  // 1/sqrt(64)
    }
    __syncthreads();

    // phase 2: qk_vec[b][h][cc*64 + c] = sum_d qh[b][d] * wk[c][d]
    {
        const int c_local = tid & 63;
        float acc[4] = {0.f, 0.f, 0.f, 0.f};
        for (int dd = 0; dd < 64; ++dd) {
            float wv = wk[c_local * 65 + dd];
            #pragma unroll
            for (int i = 0; i < 4; ++i)
                acc[i] = fmaf(qh[(w * 4 + i) * 64 + dd], wv, acc[i]);
        }
        #pragma unroll
        for (int i = 0; i < 4; ++i) {
            int b = w * 4 + i;
            qk_vec[((size_t)b * H_ + h) * KVD + cc * 64 + c_local] = acc[i];
        }
    }
}

// ---------------------------------------------------------------------------
// k_attn v9: heads-split, block-shared LDS tiles.
//
// R4 post-mortem: three latency-hiding schemes (reg-dbuf@1w, reg-dbuf@2w,
// async LDS ring + vmcnt(8)) all tie at ~100us (2.7 TB/s) -> k_attn is
// DEPENDENCY-CHAIN-bound: per row each wave ran the full serial softmax
// chain (scatter->lgkm->gather->3x shfl->expf->16 shfl) ~800-1000cy; with
// 2 waves/SIMD, period ~= chain/2 -> 2.7 TB/s. Model matches measurement.
//
// v9: stage 8-row KV tiles into LDS ONCE per block (global_load_lds,
// double-buffered, 1 barrier/tile); each of the 4 waves computes only its
// 2 exclusive heads over ALL tile rows. Per-wave per-row work drops 4x
// (16+16 FMA vs 64+64); the serial chain runs once per 4-ROW GROUP with
// 1 gather+butterfly+exp and 8 broadcast shfls. Issue ~106cy/row/wave vs
// BW-bound budget 400cy/row/block -> plenty of slack, chains overlap via
// ILP across groups. Heads wave-exclusive -> no block merge, direct atomics.
// LDS 41.5 KB, VGPR ~130.
// ---------------------------------------------------------------------------
#define SROW 68
#define T_   8   // rows per LDS tile

__device__ __forceinline__ void stage_tile(const float* __restrict__ chunkbase,
                                           int t, float (&buf)[T_][KVD],
                                           int w, int lane) {
    // wave w stages rows {2w, 2w+1} of tile t: 2 rows x 2 halves x 1 KB
    #pragma unroll
    for (int r = 0; r < 2; ++r) {
        const int row = w * 2 + r;
        const float* rowp = chunkbase + (size_t)(t * T_ + row) * KVD;
        __builtin_amdgcn_global_load_lds(
            (__attribute__((address_space(1))) unsigned int*)(rowp + lane * 4),
            (__attribute__((address_space(3))) unsigned int*)(&buf[row][0]),
            16, 0, 0);
        __builtin_amdgcn_global_load_lds(
            (__attribute__((address_space(1))) unsigned int*)(rowp + 256 + lane * 4),
            (__attribute__((address_space(3))) unsigned int*)(&buf[row][256]),
            16, 0, 0);
    }
}

template <int NC>
__global__ __launch_bounds__(256, 2) void k_attn(const float* __restrict__ kv,
                                                 const float* __restrict__ qk_vec,
                                                 float* __restrict__ ctx_acc,
                                                 float* __restrict__ l_acc) {
    constexpr int CHUNK = S_ / NC;         // NC=32 -> 256 rows/block
    constexpr int NT = CHUNK / T_;         // 32 tiles

    __shared__ __align__(16) float kbuf[2][T_][KVD];  // 32 KB double-buffered tile
    __shared__ __align__(16) float scr[4][8][SROW];   // 8.7 KB scatter (wave-private)

    const int tid = threadIdx.x;
    const int lane = tid & 63;
    const int w = tid >> 6;                // wave id; heads {2w, 2w+1}
    const int nc = blockIdx.x, b = blockIdx.y;
    const int hme = lane >> 3, seg = lane & 7;
    const int g_mine = hme >> 1;           // (row-in-group, head) pair owned by lane
    (void)g_mine;

    // wave's 2 head vectors (already scaled by 1/8 in k_prep)
    float qk2[2][8];
    {
        const float* qb = qk_vec + ((size_t)b * H_ + 2 * w) * KVD;
        #pragma unroll
        for (int hh = 0; hh < 2; ++hh) {
            float4 v0 = *(const float4*)&qb[hh * KVD + lane * 4];
            float4 v1 = *(const float4*)&qb[hh * KVD + 256 + lane * 4];
            qk2[hh][0] = v0.x; qk2[hh][1] = v0.y; qk2[hh][2] = v0.z; qk2[hh][3] = v0.w;
            qk2[hh][4] = v1.x; qk2[hh][5] = v1.y; qk2[hh][6] = v1.z; qk2[hh][7] = v1.w;
        }
    }

    float ctx2[2][8];
    #pragma unroll
    for (int hh = 0; hh < 2; ++hh)
        #pragma unroll
        for (int j = 0; j < 8; ++j) ctx2[hh][j] = 0.f;
    float l_loc = 0.f;

    const float* chunkbase = kv + ((size_t)b * S_ + (size_t)nc * CHUNK) * KVD;

    stage_tile(chunkbase, 0, kbuf[0], w, lane);
    __syncthreads();   // drains vmcnt -> tile 0 resident & visible

    int p = 0;
    #pragma unroll 1
    for (int t = 0; t < NT; ++t) {
        if (t + 1 < NT) stage_tile(chunkbase, t + 1, kbuf[p ^ 1], w, lane);
        // consume kbuf[p]: 2 groups of 4 rows, all rows, wave's 2 heads
        #pragma unroll
        for (int g2 = 0; g2 < 2; ++g2) {
            const float(&rows)[T_][KVD] = kbuf[p];
            float kvr[4][8];
            #pragma unroll
            for (int r = 0; r < 4; ++r) {
                const float* rp = &rows[g2 * 4 + r][0];
                float4 v0 = *(const float4*)&rp[lane * 4];
                float4 v1 = *(const float4*)&rp[256 + lane * 4];
                kvr[r][0] = v0.x; kvr[r][1] = v0.y; kvr[r][2] = v0.z; kvr[r][3] = v0.w;
                kvr[r][4] = v1.x; kvr[r][5] = v1.y; kvr[r][6] = v1.z; kvr[r][7] = v1.w;
            }
            // dot partials -> scatter (lanes consecutive, conflict-free)
            #pragma unroll
            for (int r = 0; r < 4; ++r)
                #pragma unroll
                for (int hh = 0; hh < 2; ++hh) {
                    float pp = 0.f;
                    #pragma unroll
                    for (int j = 0; j < 8; ++j)
                        pp = fmaf(kvr[r][j], qk2[hh][j], pp);
                    scr[w][r * 2 + hh][lane] = pp;
                }
            asm volatile("" ::: "memory");
            // gather: lane owns pair hme = (g= hme>>1, hh= hme&1)
            const float* gp = &scr[w][hme][seg * 8];
            float4 x = *(const float4*)gp;
            float4 y = *(const float4*)(gp + 4);
            float s = ((x.x + x.y) + (x.z + x.w)) + ((y.x + y.y) + (y.z + y.w));
            s += __shfl_xor(s, 1);
            s += __shfl_xor(s, 2);
            s += __shfl_xor(s, 4);
            float e = __expf(s);
            l_loc += e;   // replicated 8x per pair; divided by 8 at the end
            // broadcast weights + PV accumulate
            #pragma unroll
            for (int r = 0; r < 4; ++r)
                #pragma unroll
                for (int hh = 0; hh < 2; ++hh) {
                    float wv = __shfl(e, (r * 2 + hh) * 8 + seg);
                    #pragma unroll
                    for (int j = 0; j < 8; ++j)
                        ctx2[hh][j] = fmaf(wv, kvr[r][j], ctx2[hh][j]);
                }
        }
        __syncthreads();
        p ^= 1;
    }

    // ---- l reduction: sum lanes with same bit3 (=hh), each e counted 8x
    {
        float ls = l_loc;
        ls += __shfl_xor(ls, 1);
        ls += __shfl_xor(ls, 2);
        ls += __shfl_xor(ls, 4);
        ls += __shfl_xor(ls, 16);
        ls += __shfl_xor(ls, 32);
        ls *= 0.125f;
        if (lane == 0) atomicAdd(&l_acc[b * H_ + 2 * w], ls);
        if (lane == 8) atomicAdd(&l_acc[b * H_ + 2 * w + 1], ls);
    }

    // ---- ctx: heads are wave-exclusive within block -> direct global atomics
    {
        size_t gb = (size_t)b * (H_ * KVD);
        #pragma unroll
        for (int hh = 0; hh < 2; ++hh) {
            float* dst = &ctx_acc[gb + (size_t)(2 * w + hh) * KVD];
            #pragma unroll
            for (int j = 0; j < 4; ++j)
                atomicAdd(&dst[lane * 4 + j], ctx2[hh][j]);
            #pragma unroll
            for (int j = 4; j < 8; ++j)
                atomicAdd(&dst[256 + lane * 4 + (j - 4)], ctx2[hh][j]);
        }
    }
}

// ---------------------------------------------------------------------------
// k_ctx: ctx_buf[b][e] += (sum_{c chunk} ctx_acc[b,h(e),c]*Wv[c][e]) / l[b,h]
//        (+ bv[e] on kc==0).  grid (kc=4, b=16) x 512
// ---------------------------------------------------------------------------
__global__ __launch_bounds__(512) void k_ctx(const float* __restrict__ ctx_acc,
                                             const float* __restrict__ l_acc,
                                             const float* __restrict__ Wv,
                                             const float* __restrict__ bv,
                                             float* __restrict__ ctx_buf) {
    const int kc = blockIdx.x, b = blockIdx.y;
    const int e = threadIdx.x;
    const int h = e >> 6;
    const float inv = 1.0f / l_acc[b * H_ + h];
    const float* ca = ctx_acc + ((size_t)b * H_ + h) * KVD + kc * 128;
    const float* wv = Wv + (size_t)(kc * 128) * E_ + e;
    float a0 = 0.f, a1 = 0.f, a2 = 0.f, a3 = 0.f;
    for (int c = 0; c < 128; c += 4) {
        a0 = fmaf(ca[c],     wv[(size_t)(c)     * E_], a0);
        a1 = fmaf(ca[c + 1], wv[(size_t)(c + 1) * E_], a1);
        a2 = fmaf(ca[c + 2], wv[(size_t)(c + 2) * E_], a2);
        a3 = fmaf(ca[c + 3], wv[(size_t)(c + 3) * E_], a3);
    }
    float val = ((a0 + a1) + (a2 + a3)) * inv;
    if (kc == 0) val += bv[e];
    atomicAdd(&ctx_buf[(size_t)b * E_ + e], val);
}

// ---------------------------------------------------------------------------
// k_o: out[b][e] += sum_{i chunk} ctx_buf[b][i]*Wo[i][e] (+ bo[e] on kc==0)
// grid (kc=4, b=16) x 512
// ---------------------------------------------------------------------------
__global__ __launch_bounds__(512) void k_o(const float* __restrict__ ctx_buf,
                                           const float* __restrict__ Wo,
                                           const float* __restrict__ bo,
                                           float* __restrict__ out) {
    const int kc = blockIdx.x, b = blockIdx.y;
    const int e = threadIdx.x;
    const float* cs = ctx_buf + (size_t)b * E_ + kc * 128;
    const float* wo = Wo + (size_t)(kc * 128) * E_ + e;
    float a0 = 0.f, a1 = 0.f, a2 = 0.f, a3 = 0.f;
    for (int k = 0; k < 128; k += 4) {
        a0 = fmaf(cs[k],     wo[(size_t)(k)     * E_], a0);
        a1 = fmaf(cs[k + 1], wo[(size_t)(k + 1) * E_], a1);
        a2 = fmaf(cs[k + 2], wo[(size_t)(k + 2) * E_], a2);
        a3 = fmaf(cs[k + 3], wo[(size_t)(k + 3) * E_], a3);
    }
    float val = (a0 + a1) + (a2 + a3);
    if (kc == 0) val += bo[e];
    atomicAdd(&out[(size_t)b * E_ + e], val);
}

// ---------------------------------------------------------------------------
extern "C" void kernel_launch(void* const* d_in, const int* in_sizes, int n_in,
                              void* d_out, int out_size, void* d_ws, size_t ws_size,
                              hipStream_t stream) {
    const float* query = (const float*)d_in[0];
    const float* kv    = (const float*)d_in[1];
    const float* Wq    = (const float*)d_in[2];
    const float* bq    = (const float*)d_in[3];
    const float* Wk    = (const float*)d_in[4];
    // d_in[5] = bk: softmax-invariant per (b,h) -> unused
    const float* Wv    = (const float*)d_in[6];
    const float* bv    = (const float*)d_in[7];
    const float* Wo    = (const float*)d_in[8];
    const float* bo    = (const float*)d_in[9];
    float* out = (float*)d_out;
    float* wsf = (float*)d_ws;

    float* qk_vec  = wsf + OFF_QKVEC;
    float* l_acc   = wsf + OFF_LACC;
    float* ctx_acc = wsf + OFF_CTXACC;
    float* ctx_buf = wsf + OFF_CTXBUF;

    constexpr int NC = 32;  // 512 blocks; 2 blocks/CU resident

    k_prep<<<145, 256, 0, stream>>>(query, Wq, bq, Wk, wsf, out);
    k_attn<NC><<<dim3(NC, B_), 256, 0, stream>>>(kv, qk_vec, ctx_acc, l_acc);
    k_ctx<<<dim3(4, B_), 512, 0, stream>>>(ctx_acc, l_acc, Wv, bv, ctx_buf);
    k_o<<<dim3(4, B_), 512, 0, stream>>>(ctx_buf, Wo, bo, out);
}